// Round 7
// baseline (141.289 us; speedup 1.0000x reference)
//
#include <hip/hip_runtime.h>
#include <stdint.h>

typedef _Float16 f16;
typedef f16  f16x8 __attribute__((ext_vector_type(8)));
typedef f16  f16x4 __attribute__((ext_vector_type(4)));
typedef f16  f16x2 __attribute__((ext_vector_type(2)));
typedef float f32x4 __attribute__((ext_vector_type(4)));

#define W 512
#define H 512
#define KS 11
#define NW 4                // waves per block
#define NBLK 3072           // 48 slices * 8 ty * 8 tx (64x64 tile per block)
#define NLINES 256          // spread accumulator lines (64 B apart)
#define C1_SSIM 0.0001f
#define C2_SSIM 0.0009f
#define NTOTAL 12582912.0f

// LDS tile per image: 80 rows x 80 f32 (320 B row stride), 2 images =
// 51.2 KB -> 3 blocks/CU.  Staged by global_load_lds async DMA, issued
// GROUP-MAJOR: group g (16 rows) = 10 x 1-KB chunks (5 per image).
// Ownership: waves 0,1 take 3 chunks/group, waves 2,3 take 2.
#define LROWS 80
#define LCOLS 80            // f32 units

// Normalized separable Gaussian (ksize=11, sigma=1.5), f32 master copy.
__device__ __constant__ const float GW[KS] = {
    1.02838e-3f, 7.59876e-3f, 3.600076e-2f, 1.0936069e-1f, 2.1300554e-1f,
    2.6601172e-1f,
    2.1300554e-1f, 1.0936069e-1f, 3.600076e-2f, 7.59876e-3f, 1.02838e-3f
};

__device__ inline float ssim_px(float ux, float uy, float uxx, float uyy, float uxy) {
    const float uxuy = ux * uy;
    const float a = 2.f * uxuy + C1_SSIM;
    const float b = 2.f * (uxy - uxuy) + C2_SSIM;
    const float c = ux * ux + uy * uy + C1_SSIM;
    const float d = (uxx - ux * ux) + (uyy - uy * uy) + C2_SSIM;
    return (a * b) * __builtin_amdgcn_rcpf(c * d);
}

__device__ __forceinline__ f16x8 pack84(f32x4 a, f32x4 b) {
    f16x8 r;
    f16x2 h;
    h = __builtin_bit_cast(f16x2, __builtin_amdgcn_cvt_pkrtz(a[0], a[1]));
    r[0] = h[0]; r[1] = h[1];
    h = __builtin_bit_cast(f16x2, __builtin_amdgcn_cvt_pkrtz(a[2], a[3]));
    r[2] = h[0]; r[3] = h[1];
    h = __builtin_bit_cast(f16x2, __builtin_amdgcn_cvt_pkrtz(b[0], b[1]));
    r[4] = h[0]; r[5] = h[1];
    h = __builtin_bit_cast(f16x2, __builtin_amdgcn_cvt_pkrtz(b[2], b[3]));
    r[6] = h[0]; r[7] = h[1];
    return r;
}

// Phased wait: each wave waits EXACTLY for its own chunks newer than group
// g (issue order is PINNED group-major by sched_barrier(0) fences in the
// issue loop, so in-order vmcnt accounting is sound), then a raw s_barrier
// extends the guarantee cross-wave.  sched_barrier(0) after the barrier
// pins this group's ds_reads below the wait (rule-18 discipline).
#define WAITG(N3, N2) do {                                            \
    if (w < 2) asm volatile("s_waitcnt vmcnt(" #N3 ")" ::: "memory"); \
    else       asm volatile("s_waitcnt vmcnt(" #N2 ")" ::: "memory"); \
    __builtin_amdgcn_s_barrier();                                     \
    __builtin_amdgcn_sched_barrier(0);                                \
} while (0)

// Block = 4 waves = one 64x64 output tile.  PHASE 1: issue ALL 50 DMA
// chunks upfront, ordered group-major (10 chunks per 16-row group), order
// pinned by sched_barrier(0) at each group boundary.  PHASE 2: per-group
// counted-vmcnt drain (T3/T4): consume group g while groups g+1..4 are
// still arriving from HBM -- staging and compute overlap, HBM demand
// becomes continuous instead of bursty (the R5 limiter: bulk vmcnt(0)
// drain made each block [stage burst]->[memory-idle compute]).  No LDS
// region is ever reused, so the phase protocol has no WAR hazards.
// Border zero-padding: OOB lanes redirect their per-lane GLOBAL source to a
// zeroed workspace line (LDS dest stays wave-uniform-linear).  Compute:
// hconv D=mfma_16x16x32(img, af) with the -8-col aligned window absorbed in
// the band (d=k-n-3); vconv = two chained K=16 MFMAs on lane-local packed
// rows.  Fragment algebra identical to the verified absmax-0.0 kernels.
__global__ __launch_bounds__(256, 3)
void ssim_main(const float* __restrict__ simg, const float* __restrict__ timg,
               float* __restrict__ accum, const float* __restrict__ zbuf) {
    __shared__ __align__(16) float lds[2][LROWS * LCOLS];
    __shared__ float red[NW];

    const int tid  = threadIdx.x;
    const int w    = tid >> 6;
    const int lane = tid & 63;
    const int n    = lane & 15;
    const int q    = lane >> 4;

    const int bid = blockIdx.x;
    const int z   = bid >> 6;             // 48 slices (16 batch * 3 ch)
    const int rr  = bid & 63;
    const int ty  = rr >> 3;
    const int tx  = rr & 7;

    const float* sp = simg + ((size_t)z << 18);
    const float* tp = timg + ((size_t)z << 18);
    const int x0    = tx << 6;
    const int ybase = (ty << 6) - 5;      // stored row 0 (80 rows)
    const int xbase = x0 - 8;             // stored col 0 (80 cols, aligned)

    // ---- PHASE 1: issue all DMA chunks, group-major, order-pinned ----
    // Group g chunk c (0..9): img = c>=5, j = c%5; chunk covers image-tile
    // bytes [g*5120 + j*1024, +1024): t = j*64+lane -> row=t/20, 16B seg
    // t%20.  Wave ownership: c = w + 4k (k=0,1,2; k=2 only for w<2).
    #pragma unroll
    for (int g = 0; g < 5; ++g) {
        #pragma unroll
        for (int k = 0; k < 3; ++k) {
            const int c = w + (k << 2);
            if (c < 10) {                 // wave-uniform
                const int img = (c >= 5) ? 1 : 0;
                const int j   = img ? (c - 5) : c;
                const int t   = (j << 6) + lane;
                const int row = (t * 3277) >> 16;      // t/20, t<320
                const int cl  = t - row * 20;          // 16-B segment
                const int ry   = ybase + (g << 4) + row;
                const int gcol = xbase + (cl << 2);
                const float* src = img ? tp : sp;
                const bool ok = ((unsigned)ry < (unsigned)H) &
                                ((unsigned)gcol <= (unsigned)(W - 4));
                const float* ga = ok ? (src + ((size_t)ry << 9) + gcol) : zbuf;
                void* ldst = (char*)(&lds[img][0]) + (g * 5120 + (j << 10));
                __builtin_amdgcn_global_load_lds(
                    (const uint32_t __attribute__((address_space(1)))*)ga,
                    (uint32_t __attribute__((address_space(3)))*)ldst,
                    16, 0, 0);
            }
        }
        // Pin issue order at group granularity: vmcnt retire order == group
        // order is what makes the counted waits in PHASE 2 sound.
        __builtin_amdgcn_sched_barrier(0);
    }

    // Fragment setup overlaps the in-flight DMA.
    // hconv band (B operand, K=32): A cols start at xbase+16w => d = k-n-3.
    f16x8 af;
    #pragma unroll
    for (int j = 0; j < 8; ++j) {
        const int k = (q << 3) + j;
        const int d = k - n - 3;
        af[j] = (d >= 0 && d < KS) ? (f16)GW[d] : (f16)0.f;
    }
    // vconv bands (A operands, K=16): a1 taps in group t (d=k-n), a2 spill
    // into group t+1 (d=k+16-n).
    f16x4 a1v, a2v;
    #pragma unroll
    for (int j = 0; j < 4; ++j) {
        const int k  = (q << 2) + j;
        const int d1 = k - n;
        const int d2 = k + 16 - n;
        a1v[j] = (d1 >= 0 && d1 < KS) ? (f16)GW[d1] : (f16)0.f;
        a2v[j] = (d2 >= 0 && d2 < KS) ? (f16)GW[d2] : (f16)0.f;
    }

    // ---- PHASE 2: compute, counted-vmcnt phased drain ----
    union H4 { f16x4 v4; f16x2 v2[2]; };
    const int coff = (w << 4) + (q << 3);   // f32 col offset: 16w + 8q
    const float* ls = &lds[0][coff];
    const float* lt = &lds[1][coff];

    f16x4 ph[2][5];                        // packed hconv rows, parity dbuf
    float sum = 0.f;

    #pragma unroll
    for (int g = 0; g < 5; ++g) {
        // Wait for group g only: newer outstanding = 3*(4-g) / 2*(4-g).
        if      (g == 0) WAITG(12, 8);
        else if (g == 1) WAITG(9, 6);
        else if (g == 2) WAITG(6, 4);
        else if (g == 3) WAITG(3, 2);
        else             WAITG(0, 0);

        const int ro = ((g << 4) + n) * LCOLS;
        const f32x4 s0 = *(const f32x4*)(ls + ro);
        const f32x4 s1 = *(const f32x4*)(ls + ro + 4);
        const f32x4 t0 = *(const f32x4*)(lt + ro);
        const f32x4 t1 = *(const f32x4*)(lt + ro + 4);
        const f16x8 sf = pack84(s0, s1);
        const f16x8 tf = pack84(t0, t1);
        const int pb = g & 1;
        #pragma unroll
        for (int c = 0; c < 5; ++c) {
            f16x8 ch;
            if      (c == 0) ch = sf;
            else if (c == 1) ch = tf;
            else if (c == 2) ch = sf * sf;
            else if (c == 3) ch = tf * tf;
            else             ch = sf * tf;
            const f32x4 zero = {0.f, 0.f, 0.f, 0.f};
            const f32x4 d = __builtin_amdgcn_mfma_f32_16x16x32_f16(ch, af, zero, 0, 0, 0);
            H4 u;
            u.v2[0] = __builtin_bit_cast(f16x2, __builtin_amdgcn_cvt_pkrtz(d[0], d[1]));
            u.v2[1] = __builtin_bit_cast(f16x2, __builtin_amdgcn_cvt_pkrtz(d[2], d[3]));
            ph[pb][c] = u.v4;              // lane-local: rows 4q..4q+3 at col 16w+n
        }
        if (g >= 1) {
            const int pa = pb ^ 1;        // group t = g-1
            f32x4 acc[5];
            #pragma unroll
            for (int c = 0; c < 5; ++c) {
                const f32x4 zero = {0.f, 0.f, 0.f, 0.f};
                f32x4 a = __builtin_amdgcn_mfma_f32_16x16x16f16(a2v, ph[pb][c], zero, 0, 0, 0);
                a = __builtin_amdgcn_mfma_f32_16x16x16f16(a1v, ph[pa][c], a, 0, 0, 0);
                acc[c] = a;
            }
            #pragma unroll
            for (int rg = 0; rg < 4; ++rg)
                sum += ssim_px(acc[0][rg], acc[1][rg], acc[2][rg],
                               acc[3][rg], acc[4][rg]);
        }
    }

    // ---- Wave reduce, block reduce, one spread atomic per block ----
    #pragma unroll
    for (int off = 32; off > 0; off >>= 1)
        sum += __shfl_down(sum, off, 64);
    if (lane == 0) red[w] = sum;
    __syncthreads();
    if (tid == 0) {
        atomicAdd(&accum[(blockIdx.x & (NLINES - 1)) << 4],
                  red[0] + red[1] + red[2] + red[3]);
    }
}

__global__ void ssim_final(const float* __restrict__ accum, float* __restrict__ out) {
    const int lane = threadIdx.x;
    float s = 0.f;
    #pragma unroll
    for (int i = 0; i < NLINES / 64; ++i)
        s += accum[((i << 6) + lane) << 4];
    #pragma unroll
    for (int off = 32; off > 0; off >>= 1)
        s += __shfl_down(s, off, 64);
    if (lane == 0) out[0] = 1.f - s * (1.f / NTOTAL);
}

extern "C" void kernel_launch(void* const* d_in, const int* in_sizes, int n_in,
                              void* d_out, int out_size, void* d_ws, size_t ws_size,
                              hipStream_t stream) {
    const float* s = (const float*)d_in[0];
    const float* t = (const float*)d_in[1];
    float* out   = (float*)d_out;
    float* accum = (float*)d_ws;                 // NLINES*16 floats = 16 KB
    const float* zbuf = accum + NLINES * 16;     // zeroed line for OOB DMA

    hipMemsetAsync(accum, 0, NLINES * 16 * sizeof(float) + 256, stream);
    ssim_main<<<dim3(NBLK), 256, 0, stream>>>(s, t, accum, zbuf);
    ssim_final<<<1, 64, 0, stream>>>(accum, out);
}

// Round 10
// 137.482 us; speedup vs baseline: 1.0277x; 1.0277x over previous
//
#include <hip/hip_runtime.h>
#include <stdint.h>

typedef _Float16 f16;
typedef f16  f16x8 __attribute__((ext_vector_type(8)));
typedef f16  f16x4 __attribute__((ext_vector_type(4)));
typedef f16  f16x2 __attribute__((ext_vector_type(2)));
typedef float f32x4 __attribute__((ext_vector_type(4)));

#define W 512
#define H 512
#define KS 11
#define NW 8                // waves per block (512 threads)
#define NBLK 256            // persistent: 1 block/CU, 12 tiles each
#define NITER 12            // 3072 tiles / 256 blocks
#define NLINES 256          // one accum line per block (no atomics)
#define C1_SSIM 0.0001f
#define C2_SSIM 0.0009f
#define NTOTAL 12582912.0f

// Per-tile LDS: 80 rows x 80 f32 (320 B stride) x 2 images = 51.2 KB =
// 50 x 1-KB DMA chunks.  Two tile buffers = 102.4 KB -> 1 block/CU.
#define LCOLS 80

// Normalized separable Gaussian (ksize=11, sigma=1.5), f32 master copy.
__device__ __constant__ const float GW[KS] = {
    1.02838e-3f, 7.59876e-3f, 3.600076e-2f, 1.0936069e-1f, 2.1300554e-1f,
    2.6601172e-1f,
    2.1300554e-1f, 1.0936069e-1f, 3.600076e-2f, 7.59876e-3f, 1.02838e-3f
};

__device__ inline float ssim_px(float ux, float uy, float uxx, float uyy, float uxy) {
    const float uxuy = ux * uy;
    const float a = 2.f * uxuy + C1_SSIM;
    const float b = 2.f * (uxy - uxuy) + C2_SSIM;
    const float c = ux * ux + uy * uy + C1_SSIM;
    const float d = (uxx - ux * ux) + (uyy - uy * uy) + C2_SSIM;
    return (a * b) * __builtin_amdgcn_rcpf(c * d);
}

__device__ __forceinline__ f16x8 pack84(f32x4 a, f32x4 b) {
    f16x8 r;
    f16x2 h;
    h = __builtin_bit_cast(f16x2, __builtin_amdgcn_cvt_pkrtz(a[0], a[1]));
    r[0] = h[0]; r[1] = h[1];
    h = __builtin_bit_cast(f16x2, __builtin_amdgcn_cvt_pkrtz(a[2], a[3]));
    r[2] = h[0]; r[3] = h[1];
    h = __builtin_bit_cast(f16x2, __builtin_amdgcn_cvt_pkrtz(b[0], b[1]));
    r[4] = h[0]; r[5] = h[1];
    h = __builtin_bit_cast(f16x2, __builtin_amdgcn_cvt_pkrtz(b[2], b[3]));
    r[6] = h[0]; r[7] = h[1];
    return r;
}

// DMA-stage one tile (R5/R7-verified mapping): chunk c (0..49): img=c>=25,
// cc=c%25; per-lane 16 B at off=cc*1024+lane*16 -> row=off/320, col-byte
// off%320.  OOB lanes redirect the GLOBAL source to a zeroed workspace
// line (LDS dest stays wave-uniform-linear).  8 waves: wave w owns chunks
// c = 8k+w (waves 0,1: 7 chunks; waves 2..7: 6).  No destination
// registers -> the compiler cannot corrupt or sink this prefetch.
__device__ __forceinline__ void issue_dma(const float* __restrict__ simg,
                                          const float* __restrict__ timg,
                                          const float* __restrict__ zb,
                                          int w, int lane, int T, float* ldsbase) {
    const int z  = T >> 6;
    const int rr = T & 63;
    const int ty = rr >> 3;
    const int tx = rr & 7;
    const float* sp = simg + ((size_t)z << 18);
    const float* tp = timg + ((size_t)z << 18);
    const int ybase = (ty << 6) - 5;
    const int xbase = (tx << 6) - 8;
    #pragma unroll
    for (int k = 0; k < 7; ++k) {
        const int c = (k << 3) + w;
        if (c < 50) {                     // wave-uniform
            const int img = (c >= 25) ? 1 : 0;
            const int cc  = img ? (c - 25) : c;
            const int off = (cc << 10) + (lane << 4);
            const int t16 = off >> 6;                 // < 400
            const int row = (t16 * 205) >> 10;        // off/320
            const int colb = off - row * 320;
            const int ry   = ybase + row;
            const int gcol = xbase + (colb >> 2);
            const float* src = img ? tp : sp;
            const bool ok = ((unsigned)ry < (unsigned)H) &
                            ((unsigned)gcol <= (unsigned)(W - 4));
            const float* ga = ok ? (src + ((size_t)ry << 9) + gcol) : zb;
            void* ldst = (char*)ldsbase + (c << 10);
            __builtin_amdgcn_global_load_lds(
                (const uint32_t __attribute__((address_space(1)))*)ga,
                (uint32_t __attribute__((address_space(3)))*)ldst,
                16, 0, 0);
        }
    }
}

// Compute HALF a tile (verified fragment algebra, g = 2h + j):
// wave-half h=w>>2 owns out-rows 32h..32h+31 = vconv tiles t=2h,2h+1,
// consuming hconv groups 2h..2h+2; wave col slice cw=w&3 (16 cols).
// hconv D=mfma_16x16x32(img, af), -8-col window absorbed in the band
// (d=k-n-3); vconv = two chained K=16 MFMAs on lane-local packed rows
// (B[k][n] layout k=4*(lane>>4)+j == hconv D row layout; zero cross-lane).
__device__ __forceinline__ float compute_half(const float* __restrict__ base,
                                              int coff, int n, int h,
                                              f16x8 af, f16x4 a1v, f16x4 a2v) {
    union H4 { f16x4 v4; f16x2 v2[2]; };
    const float* ls = base + coff;
    const float* lt = base + 6400 + coff;
    f16x4 ph[2][5];
    float sum = 0.f;
    #pragma unroll
    for (int j = 0; j < 3; ++j) {
        const int g  = (h << 1) + j;
        const int ro = ((g << 4) + n) * LCOLS;
        const f32x4 s0 = *(const f32x4*)(ls + ro);
        const f32x4 s1 = *(const f32x4*)(ls + ro + 4);
        const f32x4 t0 = *(const f32x4*)(lt + ro);
        const f32x4 t1 = *(const f32x4*)(lt + ro + 4);
        const f16x8 sf = pack84(s0, s1);
        const f16x8 tf = pack84(t0, t1);
        const int pb = j & 1;
        #pragma unroll
        for (int c = 0; c < 5; ++c) {
            f16x8 ch;
            if      (c == 0) ch = sf;
            else if (c == 1) ch = tf;
            else if (c == 2) ch = sf * sf;
            else if (c == 3) ch = tf * tf;
            else             ch = sf * tf;
            const f32x4 zero = {0.f, 0.f, 0.f, 0.f};
            const f32x4 d = __builtin_amdgcn_mfma_f32_16x16x32_f16(ch, af, zero, 0, 0, 0);
            H4 u;
            u.v2[0] = __builtin_bit_cast(f16x2, __builtin_amdgcn_cvt_pkrtz(d[0], d[1]));
            u.v2[1] = __builtin_bit_cast(f16x2, __builtin_amdgcn_cvt_pkrtz(d[2], d[3]));
            ph[pb][c] = u.v4;
        }
        if (j >= 1) {
            const int pa = pb ^ 1;        // hconv group g-1 (vconv tile t=g-1)
            f32x4 acc[5];
            #pragma unroll
            for (int c = 0; c < 5; ++c) {
                const f32x4 zero = {0.f, 0.f, 0.f, 0.f};
                f32x4 a = __builtin_amdgcn_mfma_f32_16x16x16f16(a2v, ph[pb][c], zero, 0, 0, 0);
                a = __builtin_amdgcn_mfma_f32_16x16x16f16(a1v, ph[pa][c], a, 0, 0, 0);
                acc[c] = a;
            }
            #pragma unroll
            for (int rg = 0; rg < 4; ++rg)
                sum += ssim_px(acc[0][rg], acc[1][rg], acc[2][rg],
                               acc[3][rg], acc[4][rg]);
        }
    }
    return sum;
}

// Persistent pipeline: 256 blocks (1/CU), 512 threads (8 waves = 2/SIMD),
// each block owns 12 tiles (T = bid + 256*t).  Double-buffered DMA: per
// iteration issue tile t+1's 50 chunks into the idle buffer, counted wait
// vmcnt(6) (tile t landed; tile t+1 stays in flight), barrier, compute
// tile t, barrier.  Every CU holds ~50 KB of DMA in flight at all times ->
// HBM demand continuous BY CONSTRUCTION (fixing the [stage burst]->
// [memory-idle compute] duty cycle that pinned R4/R5/R7 at 46-50 us), and
// 2 waves/SIMD keep VALU/MFMA latency overlapped in the compute phase
// (the occupancy defect of the R9 variant: 256 thr = 1 wave/SIMD).
__global__ __launch_bounds__(512, 1)
void ssim_main(const float* __restrict__ simg, const float* __restrict__ timg,
               float* __restrict__ accum, const float* __restrict__ zbuf) {
    __shared__ __align__(16) float lds[2][2 * 6400];   // [buf][img-pair]
    __shared__ float red[NW];

    const int tid  = threadIdx.x;
    const int w    = tid >> 6;
    const int lane = tid & 63;
    const int n    = lane & 15;
    const int q    = lane >> 4;
    const int h    = w >> 2;              // out-row half
    const int cw   = w & 3;               // 16-col slice
    const int bid  = blockIdx.x;

    // Prologue: stage tile 0 into buf0.
    issue_dma(simg, timg, zbuf, w, lane, bid, &lds[0][0]);
    __builtin_amdgcn_sched_barrier(0);

    // Fragment setup under the in-flight DMA (verified algebra).
    f16x8 af;
    #pragma unroll
    for (int j = 0; j < 8; ++j) {
        const int k = (q << 3) + j;
        const int d = k - n - 3;
        af[j] = (d >= 0 && d < KS) ? (f16)GW[d] : (f16)0.f;
    }
    f16x4 a1v, a2v;
    #pragma unroll
    for (int j = 0; j < 4; ++j) {
        const int k  = (q << 2) + j;
        const int d1 = k - n;
        const int d2 = k + 16 - n;
        a1v[j] = (d1 >= 0 && d1 < KS) ? (f16)GW[d1] : (f16)0.f;
        a2v[j] = (d2 >= 0 && d2 < KS) ? (f16)GW[d2] : (f16)0.f;
    }

    const int coff = (cw << 4) + (q << 3);
    float sum = 0.f;

    for (int t = 0; t < NITER; ++t) {
        if (t < NITER - 1) {
            issue_dma(simg, timg, zbuf, w, lane, bid + ((t + 1) << 8),
                      &lds[(t + 1) & 1][0]);
            __builtin_amdgcn_sched_barrier(0);
            // Uniform counted wait: newest <=6 ops (tile t+1) may remain in
            // flight; everything older (all of tile t's chunks) has landed.
            asm volatile("s_waitcnt vmcnt(6)" ::: "memory");
        } else {
            asm volatile("s_waitcnt vmcnt(0)" ::: "memory");
        }
        __builtin_amdgcn_s_barrier();        // tile t visible to all waves
        __builtin_amdgcn_sched_barrier(0);

        sum += compute_half(&lds[t & 1][0], coff, n, h, af, a1v, a2v);

        __builtin_amdgcn_sched_barrier(0);
        __builtin_amdgcn_s_barrier();        // buffer free for next issue
    }

    // ---- Wave reduce, block reduce, one plain store per block ----
    #pragma unroll
    for (int off = 32; off > 0; off >>= 1)
        sum += __shfl_down(sum, off, 64);
    if (lane == 0) red[w] = sum;
    __syncthreads();
    if (tid == 0) {
        float bs = 0.f;
        #pragma unroll
        for (int i = 0; i < NW; ++i) bs += red[i];
        accum[bid << 4] = bs;
    }
}

__global__ void ssim_final(const float* __restrict__ accum, float* __restrict__ out) {
    const int lane = threadIdx.x;
    float s = 0.f;
    #pragma unroll
    for (int i = 0; i < NLINES / 64; ++i)
        s += accum[((i << 6) + lane) << 4];
    #pragma unroll
    for (int off = 32; off > 0; off >>= 1)
        s += __shfl_down(s, off, 64);
    if (lane == 0) out[0] = 1.f - s * (1.f / NTOTAL);
}

extern "C" void kernel_launch(void* const* d_in, const int* in_sizes, int n_in,
                              void* d_out, int out_size, void* d_ws, size_t ws_size,
                              hipStream_t stream) {
    const float* s = (const float*)d_in[0];
    const float* t = (const float*)d_in[1];
    float* out   = (float*)d_out;
    float* accum = (float*)d_ws;                 // NLINES*16 floats = 16 KB
    const float* zbuf = accum + NLINES * 16;     // zeroed line for OOB DMA

    hipMemsetAsync(accum, 0, NLINES * 16 * sizeof(float) + 256, stream);
    ssim_main<<<dim3(NBLK), 512, 0, stream>>>(s, t, accum, zbuf);
    ssim_final<<<1, 64, 0, stream>>>(accum, out);
}